// Round 5
// baseline (1262.736 us; speedup 1.0000x reference)
//
#include <hip/hip_runtime.h>

#define N_NODES 100000
#define D 64
#define N_EDGES 1000000
#define RPB 64                                  // dst rows per bucket
#define NBUCKETS ((N_NODES + RPB - 1) / RPB)    // 1563
#define BCAP 1024                               // edges/bucket cap (mean 640, sigma~25)
#define CUR_STRIDE 16                           // cursor padding: 1 per 64B line

// ---- binning: edge -> bucket (dst>>6), payload src | (dst&63)<<17 ----
// src < 100000 < 2^17, dlocal < 64 -> packs into 23 bits.
__global__ __launch_bounds__(256) void bin_kernel(
    const int* __restrict__ src, const int* __restrict__ dst,
    unsigned* __restrict__ binned, int* __restrict__ cursor) {
    int t = blockIdx.x * blockDim.x + threadIdx.x;
    int nthreads = gridDim.x * blockDim.x;
    for (int e = t; e < N_EDGES; e += nthreads) {
        int s = src[e], d = dst[e];
        int b = d >> 6;
        unsigned p = (unsigned)s | ((unsigned)(d & 63) << 17);
        int slot = atomicAdd(&cursor[b * CUR_STRIDE], 1);
        if (slot < BCAP) binned[(size_t)b * BCAP + slot] = p;
    }
}

// ---- per-bucket aggregation into LDS (no global atomics) ----
// Block b owns dst rows [b*64, b*64+64). 4 waves; wave handles one edge:
// lane l accumulates feat[src][l] into LDS row dlocal via ds_add_f32.
// Bank map: (row*64 + l) % 32 == l % 32 -> 2 lanes/bank == free (m136).
template <bool WRITE_CNT>
__global__ __launch_bounds__(256) void agg_kernel(
    const float* __restrict__ feat, const unsigned* __restrict__ binned,
    const int* __restrict__ cursor, float* __restrict__ agg,
    float* __restrict__ cntf) {
    __shared__ float s[RPB * D];   // 16 KB
    __shared__ float scnt[RPB];
    int b = blockIdx.x;
    int tid = threadIdx.x;
    int lane = tid & 63, wave = tid >> 6;

    for (int i = tid; i < RPB * D; i += 256) s[i] = 0.f;
    if (tid < RPB) scnt[tid] = 0.f;
    __syncthreads();

    int cnt = cursor[b * CUR_STRIDE];
    if (cnt > BCAP) cnt = BCAP;
    const unsigned* bp = binned + (size_t)b * BCAP;

    int i = wave;
    // 4-deep unroll: 4 independent gather streams per wave
    for (; i + 12 < cnt; i += 16) {
        unsigned p0 = bp[i], p1 = bp[i + 4], p2 = bp[i + 8], p3 = bp[i + 12];
        float v0 = feat[(size_t)(p0 & 0x1FFFF) * D + lane];
        float v1 = feat[(size_t)(p1 & 0x1FFFF) * D + lane];
        float v2 = feat[(size_t)(p2 & 0x1FFFF) * D + lane];
        float v3 = feat[(size_t)(p3 & 0x1FFFF) * D + lane];
        atomicAdd(&s[(p0 >> 17) * D + lane], v0);
        atomicAdd(&s[(p1 >> 17) * D + lane], v1);
        atomicAdd(&s[(p2 >> 17) * D + lane], v2);
        atomicAdd(&s[(p3 >> 17) * D + lane], v3);
        if (WRITE_CNT && lane == 0) {
            atomicAdd(&scnt[p0 >> 17], 1.f);
            atomicAdd(&scnt[p1 >> 17], 1.f);
            atomicAdd(&scnt[p2 >> 17], 1.f);
            atomicAdd(&scnt[p3 >> 17], 1.f);
        }
    }
    for (; i < cnt; i += 4) {
        unsigned p = bp[i];
        float v = feat[(size_t)(p & 0x1FFFF) * D + lane];
        atomicAdd(&s[(p >> 17) * D + lane], v);
        if (WRITE_CNT && lane == 0) atomicAdd(&scnt[p >> 17], 1.f);
    }
    __syncthreads();

    for (int r = wave; r < RPB; r += 4) {
        int n = b * RPB + r;
        if (n < N_NODES) agg[(size_t)n * D + lane] = s[r * D + lane];
    }
    if (WRITE_CNT && tid < RPB) {
        int n = b * RPB + tid;
        if (n < N_NODES) cntf[n] = scnt[tid];
    }
}

// ---- transform: out[n][j] = relu(inv*sum_k agg[n][k]Wl[k][j] + sum_k x[n][k]Wr[k][j] + b[j])
// No shfl: all 64 lanes issue the SAME-address float4 load (hardware broadcast),
// so every lane holds x[n][4c..4c+3] directly. Weights register-resident.
template <bool FUSE_OUT>
__global__ __launch_bounds__(256) void transform_kernel(
    const float* __restrict__ agg, const float* __restrict__ cntf,
    const float* __restrict__ xin,
    const float* __restrict__ Wl, const float* __restrict__ Wr,
    const float* __restrict__ bias,
    const float* __restrict__ Wc, const float* __restrict__ bc,
    float* __restrict__ out) {
    int lane = threadIdx.x & 63;

    float wl[64], wr[64];
#pragma unroll
    for (int k = 0; k < 64; ++k) {
        wl[k] = Wl[k * 64 + lane];
        wr[k] = Wr[k * 64 + lane];
    }
    float bj = bias[lane];
    float wcj = FUSE_OUT ? Wc[lane] : 0.f;
    float bcv = FUSE_OUT ? bc[0] : 0.f;

    int wave = (blockIdx.x * blockDim.x + threadIdx.x) >> 6;
    int nwaves = (gridDim.x * blockDim.x) >> 6;
    for (int n = wave; n < N_NODES; n += nwaves) {
        float inv = 1.f / fmaxf(cntf[n], 1.f);
        const float4* mrow = (const float4*)(agg + (size_t)n * D);
        const float4* xrow = (const float4*)(xin + (size_t)n * D);
        float am = 0.f, ax = 0.f;  // two independent chains
#pragma unroll
        for (int c = 0; c < 16; ++c) {
            float4 mv = mrow[c];
            float4 xv = xrow[c];
            am = fmaf(mv.x, wl[4 * c + 0], am);
            am = fmaf(mv.y, wl[4 * c + 1], am);
            am = fmaf(mv.z, wl[4 * c + 2], am);
            am = fmaf(mv.w, wl[4 * c + 3], am);
            ax = fmaf(xv.x, wr[4 * c + 0], ax);
            ax = fmaf(xv.y, wr[4 * c + 1], ax);
            ax = fmaf(xv.z, wr[4 * c + 2], ax);
            ax = fmaf(xv.w, wr[4 * c + 3], ax);
        }
        float acc = fmaxf(fmaf(am, inv, ax + bj), 0.f);  // mean = sum*inv folded
        if (FUSE_OUT) {
            float v = acc * wcj;
#pragma unroll
            for (int off = 32; off; off >>= 1) v += __shfl_xor(v, off);
            if (lane == 0) out[n] = v + bcv;
        } else {
            out[(size_t)n * D + lane] = acc;
        }
    }
}

extern "C" void kernel_launch(void* const* d_in, const int* in_sizes, int n_in,
                              void* d_out, int out_size, void* d_ws, size_t ws_size,
                              hipStream_t stream) {
    const float* x   = (const float*)d_in[0];
    const int* ei    = (const int*)d_in[1];  // [2, N_EDGES] int32
    const float* W1l = (const float*)d_in[2];
    const float* W1r = (const float*)d_in[3];
    const float* b1  = (const float*)d_in[4];
    const float* W2l = (const float*)d_in[5];
    const float* W2r = (const float*)d_in[6];
    const float* b2  = (const float*)d_in[7];
    const float* Wc  = (const float*)d_in[8];
    const float* bc  = (const float*)d_in[9];
    float* out = (float*)d_out;

    const int* src = ei;
    const int* dst = ei + N_EDGES;

    // ws layout: cursor i32[NB*16] | binned u32[NB*BCAP] | agg f32[N*D] | cnt f32[N] | h1 f32[N*D]
    char* w = (char*)d_ws;
    int*      cursor = (int*)w;                 w += (size_t)NBUCKETS * CUR_STRIDE * 4;  // 100 KB
    unsigned* binned = (unsigned*)w;            w += (size_t)NBUCKETS * BCAP * 4;        // 6.4 MB
    float*    agg    = (float*)w;               w += (size_t)N_NODES * D * 4;            // 25.6 MB
    float*    cntf   = (float*)w;               w += (size_t)N_NODES * 4;                // 0.4 MB
    float*    h1     = (float*)w;                                                       // 25.6 MB

    // ---- bin once (reused by both layers) ----
    hipMemsetAsync(cursor, 0, (size_t)NBUCKETS * CUR_STRIDE * 4, stream);
    bin_kernel<<<1024, 256, 0, stream>>>(src, dst, binned, cursor);

    // ---- layer 1 ----
    agg_kernel<true><<<NBUCKETS, 256, 0, stream>>>(x, binned, cursor, agg, cntf);
    transform_kernel<false><<<1024, 256, 0, stream>>>(
        agg, cntf, x, W1l, W1r, b1, nullptr, nullptr, h1);

    // ---- layer 2 + fused classifier ----
    agg_kernel<false><<<NBUCKETS, 256, 0, stream>>>(h1, binned, cursor, agg, cntf);
    transform_kernel<true><<<1024, 256, 0, stream>>>(
        agg, cntf, h1, W2l, W2r, b2, Wc, bc, out);
}

// Round 8
// 659.323 us; speedup vs baseline: 1.9152x; 1.9152x over previous
//
#include <hip/hip_runtime.h>

#define N_NODES 100000
#define D 64
#define N_EDGES 1000000

// ---- pass A: in-degree count ----
__global__ __launch_bounds__(256) void count_kernel(
    const int* __restrict__ dst, int* __restrict__ cnt) {
    int t = blockIdx.x * blockDim.x + threadIdx.x;
    int nt = gridDim.x * blockDim.x;
    for (int e = t; e < N_EDGES; e += nt) atomicAdd(&cnt[dst[e]], 1);
}

// ---- pass B: segment offsets. Wave-local prefix sum + ONE atomic per wave.
// Allocation order across waves is nondeterministic -> segment placement varies
// per replay, but per-node sums commute (fp tolerance covers order jitter).
__global__ __launch_bounds__(256) void scan_kernel(
    const int* __restrict__ cnt, int* __restrict__ offset,
    int* __restrict__ wcur, int* __restrict__ total) {
    int n = blockIdx.x * blockDim.x + threadIdx.x;
    int lane = threadIdx.x & 63;
    int c = (n < N_NODES) ? cnt[n] : 0;
    // inclusive wave prefix
    int pre = c;
#pragma unroll
    for (int off = 1; off < 64; off <<= 1) {
        int t = __shfl_up(pre, off);
        if (lane >= off) pre += t;
    }
    int base = 0;
    if (lane == 63) base = atomicAdd(total, pre);  // lane63's pre == wave sum
    base = __shfl(base, 63);
    if (n < N_NODES) {
        int o = base + pre - c;  // exclusive
        offset[n] = o;
        wcur[n] = o;
    }
}

// ---- pass C: fill CSR ----
__global__ __launch_bounds__(256) void fill_kernel(
    const int* __restrict__ src, const int* __restrict__ dst,
    int* __restrict__ wcur, int* __restrict__ binned) {
    int t = blockIdx.x * blockDim.x + threadIdx.x;
    int nt = gridDim.x * blockDim.x;
    for (int e = t; e < N_EDGES; e += nt) {
        int pos = atomicAdd(&wcur[dst[e]], 1);
        binned[pos] = src[e];
    }
}

// ---- aggregation: one wave per node, register accumulation, mean folded in.
// lane l owns feature l; 4 independent gather chains hide latency.
__global__ __launch_bounds__(256) void agg_kernel(
    const float* __restrict__ feat, const int* __restrict__ binned,
    const int* __restrict__ offset, const int* __restrict__ cnt,
    float* __restrict__ mean_out) {
    int wave = (blockIdx.x * blockDim.x + threadIdx.x) >> 6;
    int lane = threadIdx.x & 63;
    int nw = (gridDim.x * blockDim.x) >> 6;
    for (int n = wave; n < N_NODES; n += nw) {
        int c = cnt[n];
        int o = offset[n];
        float a0 = 0.f, a1 = 0.f, a2 = 0.f, a3 = 0.f;
        int i = 0;
        for (; i + 3 < c; i += 4) {
            int s0 = binned[o + i], s1 = binned[o + i + 1];
            int s2 = binned[o + i + 2], s3 = binned[o + i + 3];
            a0 += feat[((size_t)s0 << 6) + lane];
            a1 += feat[((size_t)s1 << 6) + lane];
            a2 += feat[((size_t)s2 << 6) + lane];
            a3 += feat[((size_t)s3 << 6) + lane];
        }
        for (; i < c; ++i) a0 += feat[((size_t)binned[o + i] << 6) + lane];
        float m = (a0 + a1) + (a2 + a3);
        m = (c > 0) ? m / (float)c : 0.f;  // mean = agg/max(cnt,1); c==0 -> 0
        mean_out[((size_t)n << 6) + lane] = m;
    }
}

// ---- transform: out[n][j] = relu(sum_k mean[n][k]Wl[k][j] + sum_k x[n][k]Wr[k][j] + b[j])
// mean is pre-divided. No shfl: all 64 lanes load the SAME float4 address
// (hardware broadcast); weights register-resident (128 VGPR).
template <bool FUSE_OUT>
__global__ __launch_bounds__(256) void transform_kernel(
    const float* __restrict__ mean, const float* __restrict__ xin,
    const float* __restrict__ Wl, const float* __restrict__ Wr,
    const float* __restrict__ bias,
    const float* __restrict__ Wc, const float* __restrict__ bc,
    float* __restrict__ out) {
    int lane = threadIdx.x & 63;

    float wl[64], wr[64];
#pragma unroll
    for (int k = 0; k < 64; ++k) {
        wl[k] = Wl[k * 64 + lane];
        wr[k] = Wr[k * 64 + lane];
    }
    float bj = bias[lane];
    float wcj = FUSE_OUT ? Wc[lane] : 0.f;
    float bcv = FUSE_OUT ? bc[0] : 0.f;

    int wave = (blockIdx.x * blockDim.x + threadIdx.x) >> 6;
    int nwaves = (gridDim.x * blockDim.x) >> 6;
    for (int n = wave; n < N_NODES; n += nwaves) {
        const float4* mrow = (const float4*)(mean + ((size_t)n << 6));
        const float4* xrow = (const float4*)(xin + ((size_t)n << 6));
        float am = 0.f, ax = 0.f;  // two independent FMA chains
#pragma unroll
        for (int ci = 0; ci < 16; ++ci) {
            float4 mv = mrow[ci];
            float4 xv = xrow[ci];
            am = fmaf(mv.x, wl[4 * ci + 0], am);
            am = fmaf(mv.y, wl[4 * ci + 1], am);
            am = fmaf(mv.z, wl[4 * ci + 2], am);
            am = fmaf(mv.w, wl[4 * ci + 3], am);
            ax = fmaf(xv.x, wr[4 * ci + 0], ax);
            ax = fmaf(xv.y, wr[4 * ci + 1], ax);
            ax = fmaf(xv.z, wr[4 * ci + 2], ax);
            ax = fmaf(xv.w, wr[4 * ci + 3], ax);
        }
        float acc = fmaxf(am + ax + bj, 0.f);  // relu
        if (FUSE_OUT) {
            float v = acc * wcj;
#pragma unroll
            for (int off = 32; off; off >>= 1) v += __shfl_xor(v, off);
            if (lane == 0) out[n] = v + bcv;
        } else {
            out[((size_t)n << 6) + lane] = acc;
        }
    }
}

extern "C" void kernel_launch(void* const* d_in, const int* in_sizes, int n_in,
                              void* d_out, int out_size, void* d_ws, size_t ws_size,
                              hipStream_t stream) {
    const float* x   = (const float*)d_in[0];
    const int* ei    = (const int*)d_in[1];  // [2, N_EDGES] int32
    const float* W1l = (const float*)d_in[2];
    const float* W1r = (const float*)d_in[3];
    const float* b1  = (const float*)d_in[4];
    const float* W2l = (const float*)d_in[5];
    const float* W2r = (const float*)d_in[6];
    const float* b2  = (const float*)d_in[7];
    const float* Wc  = (const float*)d_in[8];
    const float* bc  = (const float*)d_in[9];
    float* out = (float*)d_out;

    const int* src = ei;
    const int* dst = ei + N_EDGES;

    // ws: cnt i32[N] | total i32[16pad] | offset i32[N] | wcur i32[N]
    //     | binned i32[E] | meanbuf f32[N*D] | h1 f32[N*D]   => ~56.5 MB
    char* w = (char*)d_ws;
    int*   cnt     = (int*)w;      w += (size_t)N_NODES * 4;
    int*   total   = (int*)w;      w += 16 * 4;
    int*   offset  = (int*)w;      w += (size_t)N_NODES * 4;
    int*   wcur    = (int*)w;      w += (size_t)N_NODES * 4;
    int*   binned  = (int*)w;      w += (size_t)N_EDGES * 4;
    float* meanbuf = (float*)w;    w += (size_t)N_NODES * D * 4;
    float* h1      = (float*)w;

    // ---- build CSR once (shared by both layers) ----
    hipMemsetAsync(cnt, 0, ((size_t)N_NODES + 16) * 4, stream);  // cnt + total
    count_kernel<<<2048, 256, 0, stream>>>(dst, cnt);
    scan_kernel<<<(N_NODES + 255) / 256, 256, 0, stream>>>(cnt, offset, wcur, total);
    fill_kernel<<<2048, 256, 0, stream>>>(src, dst, wcur, binned);

    // ---- layer 1 ----
    agg_kernel<<<2048, 256, 0, stream>>>(x, binned, offset, cnt, meanbuf);
    transform_kernel<false><<<1024, 256, 0, stream>>>(
        meanbuf, x, W1l, W1r, b1, nullptr, nullptr, h1);

    // ---- layer 2 + fused classifier ----
    agg_kernel<<<2048, 256, 0, stream>>>(h1, binned, offset, cnt, meanbuf);
    transform_kernel<true><<<1024, 256, 0, stream>>>(
        meanbuf, h1, W2l, W2r, b2, Wc, bc, out);
}

// Round 10
// 600.863 us; speedup vs baseline: 2.1015x; 1.0973x over previous
//
#include <hip/hip_runtime.h>

#define N_NODES 100000
#define D 64
#define N_EDGES 1000000

// ---- pass A: in-degree count ----
__global__ __launch_bounds__(256) void count_kernel(
    const int* __restrict__ dst, int* __restrict__ cnt) {
    int t = blockIdx.x * blockDim.x + threadIdx.x;
    int nt = gridDim.x * blockDim.x;
    for (int e = t; e < N_EDGES; e += nt) atomicAdd(&cnt[dst[e]], 1);
}

// ---- pass B: segment offsets. Wave-local prefix sum + ONE atomic per wave.
__global__ __launch_bounds__(256) void scan_kernel(
    const int* __restrict__ cnt, int* __restrict__ offset,
    int* __restrict__ wcur, int* __restrict__ total) {
    int n = blockIdx.x * blockDim.x + threadIdx.x;
    int lane = threadIdx.x & 63;
    int c = (n < N_NODES) ? cnt[n] : 0;
    int pre = c;
#pragma unroll
    for (int off = 1; off < 64; off <<= 1) {
        int t = __shfl_up(pre, off);
        if (lane >= off) pre += t;
    }
    int base = 0;
    if (lane == 63) base = atomicAdd(total, pre);  // lane63's pre == wave sum
    base = __shfl(base, 63);
    if (n < N_NODES) {
        int o = base + pre - c;  // exclusive
        offset[n] = o;
        wcur[n] = o;
    }
}

// ---- pass C: fill CSR ----
__global__ __launch_bounds__(256) void fill_kernel(
    const int* __restrict__ src, const int* __restrict__ dst,
    int* __restrict__ wcur, int* __restrict__ binned) {
    int t = blockIdx.x * blockDim.x + threadIdx.x;
    int nt = gridDim.x * blockDim.x;
    for (int e = t; e < N_EDGES; e += nt) {
        int pos = atomicAdd(&wcur[dst[e]], 1);
        binned[pos] = src[e];
    }
}

// ---- aggregation: one wave per node, register accumulation, mean folded in.
__global__ __launch_bounds__(256) void agg_kernel(
    const float* __restrict__ feat, const int* __restrict__ binned,
    const int* __restrict__ offset, const int* __restrict__ cnt,
    float* __restrict__ mean_out) {
    int wave = (blockIdx.x * blockDim.x + threadIdx.x) >> 6;
    int lane = threadIdx.x & 63;
    int nw = (gridDim.x * blockDim.x) >> 6;
    for (int n = wave; n < N_NODES; n += nw) {
        int c = cnt[n];
        int o = offset[n];
        float a0 = 0.f, a1 = 0.f, a2 = 0.f, a3 = 0.f;
        int i = 0;
        for (; i + 3 < c; i += 4) {
            int s0 = binned[o + i], s1 = binned[o + i + 1];
            int s2 = binned[o + i + 2], s3 = binned[o + i + 3];
            a0 += feat[((size_t)s0 << 6) + lane];
            a1 += feat[((size_t)s1 << 6) + lane];
            a2 += feat[((size_t)s2 << 6) + lane];
            a3 += feat[((size_t)s3 << 6) + lane];
        }
        for (; i < c; ++i) a0 += feat[((size_t)binned[o + i] << 6) + lane];
        float m = (a0 + a1) + (a2 + a3);
        m = (c > 0) ? m / (float)c : 0.f;
        mean_out[((size_t)n << 6) + lane] = m;
    }
}

// ---- matmul pass A (IN-PLACE): buf[n][j] <- sum_k buf[n][k] * W[k][j]
// One wave per node; lane j holds W column j in 64 VGPRs (no 128-reg monster
// -> no spill). All lanes broadcast-load the row (same-address float4), so
// every read of buf[n][*] completes before lane j overwrites buf[n][j].
__global__ __launch_bounds__(256, 3) void matA_kernel(
    float* __restrict__ buf, const float* __restrict__ W) {
    int lane = threadIdx.x & 63;
    float wcol[64];
#pragma unroll
    for (int k = 0; k < 64; ++k) wcol[k] = W[k * 64 + lane];

    int wave = (blockIdx.x * blockDim.x + threadIdx.x) >> 6;
    int nw = (gridDim.x * blockDim.x) >> 6;
    for (int n = wave; n < N_NODES; n += nw) {
        const float4* row = (const float4*)(buf + ((size_t)n << 6));
        float acc0 = 0.f, acc1 = 0.f;
#pragma unroll
        for (int c = 0; c < 16; c += 2) {  // load-consume in pairs: <=2 float4 live
            float4 v0 = row[c];
            float4 v1 = row[c + 1];
            acc0 = fmaf(v0.x, wcol[4 * c + 0], acc0);
            acc0 = fmaf(v0.y, wcol[4 * c + 1], acc0);
            acc0 = fmaf(v0.z, wcol[4 * c + 2], acc0);
            acc0 = fmaf(v0.w, wcol[4 * c + 3], acc0);
            acc1 = fmaf(v1.x, wcol[4 * c + 4], acc1);
            acc1 = fmaf(v1.y, wcol[4 * c + 5], acc1);
            acc1 = fmaf(v1.z, wcol[4 * c + 6], acc1);
            acc1 = fmaf(v1.w, wcol[4 * c + 7], acc1);
        }
        buf[((size_t)n << 6) + lane] = acc0 + acc1;
    }
}

// ---- matmul pass B: out[n][j] = relu(acc_in[n][j] + sum_k x[n][k]W[k][j] + b[j])
// FUSE: out[n] = sum_j h[n][j]*Wc[j] + bc  (wave shfl reduction)
template <bool FUSE_OUT>
__global__ __launch_bounds__(256, 3) void matB_kernel(
    const float* __restrict__ acc_in, const float* __restrict__ xin,
    const float* __restrict__ W, const float* __restrict__ bias,
    const float* __restrict__ Wc, const float* __restrict__ bc,
    float* __restrict__ out) {
    int lane = threadIdx.x & 63;
    float wcol[64];
#pragma unroll
    for (int k = 0; k < 64; ++k) wcol[k] = W[k * 64 + lane];
    float bj = bias[lane];
    float wcj = FUSE_OUT ? Wc[lane] : 0.f;
    float bcv = FUSE_OUT ? bc[0] : 0.f;

    int wave = (blockIdx.x * blockDim.x + threadIdx.x) >> 6;
    int nw = (gridDim.x * blockDim.x) >> 6;
    for (int n = wave; n < N_NODES; n += nw) {
        float a = acc_in[((size_t)n << 6) + lane];
        const float4* row = (const float4*)(xin + ((size_t)n << 6));
        float acc0 = a + bj, acc1 = 0.f;
#pragma unroll
        for (int c = 0; c < 16; c += 2) {
            float4 v0 = row[c];
            float4 v1 = row[c + 1];
            acc0 = fmaf(v0.x, wcol[4 * c + 0], acc0);
            acc0 = fmaf(v0.y, wcol[4 * c + 1], acc0);
            acc0 = fmaf(v0.z, wcol[4 * c + 2], acc0);
            acc0 = fmaf(v0.w, wcol[4 * c + 3], acc0);
            acc1 = fmaf(v1.x, wcol[4 * c + 4], acc1);
            acc1 = fmaf(v1.y, wcol[4 * c + 5], acc1);
            acc1 = fmaf(v1.z, wcol[4 * c + 6], acc1);
            acc1 = fmaf(v1.w, wcol[4 * c + 7], acc1);
        }
        float h = fmaxf(acc0 + acc1, 0.f);  // relu
        if (FUSE_OUT) {
            float v = h * wcj;
#pragma unroll
            for (int off = 32; off; off >>= 1) v += __shfl_xor(v, off);
            if (lane == 0) out[n] = v + bcv;
        } else {
            out[((size_t)n << 6) + lane] = h;
        }
    }
}

extern "C" void kernel_launch(void* const* d_in, const int* in_sizes, int n_in,
                              void* d_out, int out_size, void* d_ws, size_t ws_size,
                              hipStream_t stream) {
    const float* x   = (const float*)d_in[0];
    const int* ei    = (const int*)d_in[1];  // [2, N_EDGES] int32
    const float* W1l = (const float*)d_in[2];
    const float* W1r = (const float*)d_in[3];
    const float* b1  = (const float*)d_in[4];
    const float* W2l = (const float*)d_in[5];
    const float* W2r = (const float*)d_in[6];
    const float* b2  = (const float*)d_in[7];
    const float* Wc  = (const float*)d_in[8];
    const float* bc  = (const float*)d_in[9];
    float* out = (float*)d_out;

    const int* src = ei;
    const int* dst = ei + N_EDGES;

    // ws: cnt i32[N] | total i32[16] | offset i32[N] | wcur i32[N]
    //     | binned i32[E] | meanbuf f32[N*D] | h1 f32[N*D]   => ~56.5 MB
    char* w = (char*)d_ws;
    int*   cnt     = (int*)w;      w += (size_t)N_NODES * 4;
    int*   total   = (int*)w;      w += 16 * 4;
    int*   offset  = (int*)w;      w += (size_t)N_NODES * 4;
    int*   wcur    = (int*)w;      w += (size_t)N_NODES * 4;
    int*   binned  = (int*)w;      w += (size_t)N_EDGES * 4;
    float* meanbuf = (float*)w;    w += (size_t)N_NODES * D * 4;
    float* h1      = (float*)w;

    // ---- build CSR once (shared by both layers) ----
    hipMemsetAsync(cnt, 0, ((size_t)N_NODES + 16) * 4, stream);  // cnt + total
    count_kernel<<<2048, 256, 0, stream>>>(dst, cnt);
    scan_kernel<<<(N_NODES + 255) / 256, 256, 0, stream>>>(cnt, offset, wcur, total);
    fill_kernel<<<2048, 256, 0, stream>>>(src, dst, wcur, binned);

    // ---- layer 1 ----
    agg_kernel<<<2048, 256, 0, stream>>>(x, binned, offset, cnt, meanbuf);
    matA_kernel<<<2048, 256, 0, stream>>>(meanbuf, W1l);                 // meanbuf @= W1l
    matB_kernel<false><<<2048, 256, 0, stream>>>(
        meanbuf, x, W1r, b1, nullptr, nullptr, h1);                      // h1 = relu(. + x@W1r + b1)

    // ---- layer 2 + fused classifier ----
    agg_kernel<<<2048, 256, 0, stream>>>(h1, binned, offset, cnt, meanbuf);
    matA_kernel<<<2048, 256, 0, stream>>>(meanbuf, W2l);                 // meanbuf @= W2l
    matB_kernel<true><<<2048, 256, 0, stream>>>(
        meanbuf, h1, W2r, b2, Wc, bc, out);                              // out = (relu(...))@Wc + bc
}